// Round 10
// baseline (339.181 us; speedup 1.0000x reference)
//
#include <hip/hip_runtime.h>

// Problem constants
#define H_HEADS 16
#define KV_HEADS 8
#define DHEAD 128
#define HID 2048
#define NQ 1024
#define SCACHE 8192
#define CPOS 4096
#define SEFF 5120

typedef __attribute__((ext_vector_type(8))) __bf16 bf16x8;
typedef __attribute__((ext_vector_type(4))) float f32x4;
typedef unsigned short u16;
typedef unsigned int u32;

__device__ __forceinline__ u16 f2b(float f) {  // f32 -> bf16 bits, RNE
  u32 u = __float_as_uint(f);
  u += 0x7fffu + ((u >> 16) & 1u);
  return (u16)(u >> 16);
}
__device__ __forceinline__ u16 f2b_t(float f) {  // truncating (for P only)
  return (u16)(__float_as_uint(f) >> 16);
}
__device__ __forceinline__ float b2f(u16 b) { return __uint_as_float(((u32)b) << 16); }
__device__ __forceinline__ u32 pk2(u16 a, u16 b) { return (u32)a | ((u32)b << 16); }
__device__ __forceinline__ uint2 f4b4(float4 v) {
  uint2 o;
  o.x = pk2(f2b(v.x), f2b(v.y));
  o.y = pk2(f2b(v.z), f2b(v.w));
  return o;
}

// async global->LDS, 16B per lane (gfx950). LDS dest must be wave-uniform base
// + lane*16 — callers keep the LDS layout linear in lane order.
__device__ __forceinline__ void gld16(const u16* g, u16* l) {
  __builtin_amdgcn_global_load_lds((const __attribute__((address_space(1))) void*)g,
                                   (__attribute__((address_space(3))) void*)l, 16, 0, 0);
}

union U4 { uint4 v; u16 u[8]; };

// Merged prep kernel (R8): transpose_h | prep_vT32 | streaming converts.
//   bx <  512           : transpose_h block  (c0=(bx&31)*64, q0=(bx>>5)*64)
//   bx < 1536           : prep_vT32 block    (pb=bx-512: s0=(pb&127)*32, kv=pb>>7)
//   else                : streaming converts (W -> Wb, kcache -> kb)
__global__ void __launch_bounds__(256) k_prep_all(
    const float* __restrict__ hid, u16* __restrict__ hT,
    const float* __restrict__ vc, u16* __restrict__ vT,
    const float* __restrict__ Wq, const float* __restrict__ Wk,
    const float* __restrict__ Wv, const float* __restrict__ kc,
    u16* __restrict__ Wb, u16* __restrict__ kb) {
  __shared__ __align__(16) float ls[64 * 68];  // 17.4 KB; prep_vT32 uses 32*132 <= this
  int t = threadIdx.x;
  int bx = blockIdx.x;
  if (bx < 512) {  // ---- transpose_h ----
    int c0 = (bx & 31) * 64, q0 = (bx >> 5) * 64;
#pragma unroll
    for (int it = 0; it < 4; ++it) {
      int c = it * 256 + t;
      int row = c >> 4, ch = c & 15;
      *(float4*)(ls + row * 68 + ch * 4) =
          *(const float4*)(hid + (size_t)(c0 + row) * NQ + q0 + ch * 4);
    }
    __syncthreads();
    int ql = t & 63, cch = t >> 6;
    u32 ob[8];
#pragma unroll
    for (int j = 0; j < 8; ++j)
      ob[j] = pk2(f2b(ls[(cch * 16 + 2 * j) * 68 + ql]), f2b(ls[(cch * 16 + 2 * j + 1) * 68 + ql]));
    uint4* dst = (uint4*)(hT + (size_t)(q0 + ql) * HID + c0 + cch * 16);
    dst[0] = make_uint4(ob[0], ob[1], ob[2], ob[3]);
    dst[1] = make_uint4(ob[4], ob[5], ob[6], ob[7]);
    return;
  }
  if (bx < 1536) {  // ---- prep_vT, 32 s-rows per block ----
    int pb = bx - 512;
    int s0 = (pb & 127) * 32;
    int kv = pb >> 7;
#pragma unroll
    for (int it = 0; it < 4; ++it) {  // 32 rows x 128 cols = 1024 float4
      int c = it * 256 + t;
      int row = c >> 5, ch = c & 31;
      *(float4*)(ls + row * 132 + ch * 4) =
          *(const float4*)(vc + ((size_t)kv * SCACHE + s0 + row) * DHEAD + ch * 4);
    }
    __syncthreads();
    int d = t >> 1, half = t & 1;  // each thread: 16 s-values of one d-row
    u32 ob[8];
#pragma unroll
    for (int j = 0; j < 8; ++j)
      ob[j] = pk2(f2b(ls[(half * 16 + 2 * j) * 132 + d]), f2b(ls[(half * 16 + 2 * j + 1) * 132 + d]));
    uint4* dst = (uint4*)(vT + ((size_t)kv * DHEAD + d) * SEFF + s0 + half * 16);
    dst[0] = make_uint4(ob[0], ob[1], ob[2], ob[3]);
    dst[1] = make_uint4(ob[4], ob[5], ob[6], ob[7]);
    return;
  }
  // ---- streaming converts ----
  int i = (bx - 1536) * 256 + t;
  if (i < 2097152) {  // Wq|Wk|Wv f32 -> Wb bf16
    const float* src;
    int off;
    if (i < 1048576) { src = Wq; off = i; }
    else if (i < 1572864) { src = Wk; off = i - 1048576; }
    else { src = Wv; off = i - 1572864; }
    float4 v = ((const float4*)src)[off];
    *(uint2*)(Wb + (size_t)i * 4) = f4b4(v);
  } else {  // kcache f32 -> kb bf16
    int j = i - 2097152;
    int kvi = j >> 17;
    int rem = j & 131071;
    float4 v = *(const float4*)(kc + (size_t)kvi * SCACHE * DHEAD + (size_t)rem * 4);
    *(uint2*)(kb + (size_t)kvi * SEFF * DHEAD + (size_t)rem * 4) = f4b4(v);
  }
}

// Transposing RoPE + V-new copy:
//   hh < 16 : qkv q-part -> qb (h,q,d) [scaled]
//   hh < 24 : qkv k-part -> kb rows CPOS+q
//   hh >= 24: qkv v-part rows (d-major) -> vT s in [CPOS, SEFF), 64 blocks
__global__ void __launch_bounds__(256) k_rope_t(const u16* __restrict__ qkv,
                                                const float* __restrict__ cosb,
                                                const float* __restrict__ sinb,
                                                u16* __restrict__ qb,
                                                u16* __restrict__ kb,
                                                u16* __restrict__ vT) {
  __shared__ __align__(16) u16 ls[64 * 136];  // [q][d]
  int t = threadIdx.x;
  int hh = blockIdx.x;
  if (hh >= 24) {  // V-copy: 131072 uint4 chunks over 64 blocks x 8 iters
    int blk = (hh - 24) * 16 + blockIdx.y;  // 0..63
#pragma unroll
    for (int it = 0; it < 8; ++it) {
      int i = blk * 2048 + it * 256 + t;
      int row = i >> 7, ch = i & 127;
      *(uint4*)(vT + (size_t)row * SEFF + CPOS + ch * 8) =
          *(const uint4*)(qkv + (size_t)(3072 + row) * NQ + ch * 8);
    }
    return;
  }
  int q0 = blockIdx.y * 64;
  bool isq = hh < 16;
  int rowbase = isq ? hh * DHEAD : HID + (hh - 16) * DHEAD;
#pragma unroll
  for (int it = 0; it < 4; ++it) {
    int c = it * 256 + t;
    int d = c >> 3, qc = (c & 7) * 8;
    U4 v;
    v.v = *(const uint4*)(qkv + (size_t)(rowbase + d) * NQ + q0 + qc);
#pragma unroll
    for (int e = 0; e < 8; ++e) ls[(qc + e) * 136 + d] = v.u[e];
  }
  __syncthreads();
  int ql = t & 63, hf = t >> 6;
  int q = q0 + ql;
  float scale = isq ? 0.08838834764831845f : 1.0f;
  u16* dst = isq ? (qb + ((size_t)hh * NQ + q) * DHEAD)
                 : (kb + ((size_t)(hh - 16) * SEFF + CPOS + q) * DHEAD);
#pragma unroll
  for (int g = 0; g < 4; ++g) {
    int d0 = hf * 32 + g * 8;
    U4 x, y;
    x.v = *(uint4*)(ls + ql * 136 + d0);
    y.v = *(uint4*)(ls + ql * 136 + (d0 ^ 64));
    float4 ca = *(const float4*)(cosb + (size_t)q * DHEAD + d0);
    float4 cb = *(const float4*)(cosb + (size_t)q * DHEAD + d0 + 4);
    float4 sa = *(const float4*)(sinb + (size_t)q * DHEAD + d0);
    float4 sb = *(const float4*)(sinb + (size_t)q * DHEAD + d0 + 4);
    float cs[8] = {ca.x, ca.y, ca.z, ca.w, cb.x, cb.y, cb.z, cb.w};
    float sn[8] = {sa.x, sa.y, sa.z, sa.w, sb.x, sb.y, sb.z, sb.w};
    float sgn = (d0 < 64) ? -1.0f : 1.0f;
    u32 ob[4];
#pragma unroll
    for (int e = 0; e < 4; ++e) {
      float r0 = (b2f(x.u[2 * e]) * cs[2 * e] + sgn * b2f(y.u[2 * e]) * sn[2 * e]) * scale;
      float r1 = (b2f(x.u[2 * e + 1]) * cs[2 * e + 1] + sgn * b2f(y.u[2 * e + 1]) * sn[2 * e + 1]) * scale;
      ob[e] = pk2(f2b(r0), f2b(r1));
    }
    *(uint4*)(dst + d0) = make_uint4(ob[0], ob[1], ob[2], ob[3]);
  }
}

// GEMM1: qkv = Wb @ hT^T + bias. Round 10: 128x128 tiles, BK=64, 512 threads
// (8 waves, 2m x 4n), dbuf gld16. Rationale: total STAGED bytes = unique_A x
// n_tiles + unique_B x m_tiles; 64^2 tiles staged 525 MB through L2/L3 per
// dispatch (the hidden cost), 128^2 halves it to 262 MB. Grid (8,32) with
// n-tile FASTEST -> linear id mod 8 = n-tile -> all 32 blocks sharing a
// B-panel (512 KB) land on ONE XCD, co-resident, B L2-resident; A-panels
// serve from L3. 16 MFMA/wave between barriers (was 8).
__global__ void __launch_bounds__(512) k_gemm_qkv(
    const u16* __restrict__ Wb, const u16* __restrict__ hT, u16* __restrict__ qkv,
    const float* __restrict__ bq, const float* __restrict__ bk, const float* __restrict__ bv) {
  __shared__ __align__(16) u16 lsA[2][2][128 * 32];  // [dbuf][khalf][row*32+col]
  __shared__ __align__(16) u16 lsB[2][2][128 * 32];
  int t = threadIdx.x;
  int n0 = blockIdx.x * 128, m0 = blockIdx.y * 128;
  const u16* Abase = Wb + (size_t)m0 * HID;
  const u16* Bbase = hT + (size_t)n0 * HID;
  int lane = t & 63, wid = t >> 6;
  int quad = lane >> 4, l15 = lane & 15;
  int wr = wid >> 2, wc = wid & 3;  // 2m x 4n wave grid; per-wave 64m x 32n
  int sr = t >> 2, scol = (t & 3) * 8;  // staging: 512 chunks/khalf, 1/thread
  f32x4 acc[4][2];
#pragma unroll
  for (int i = 0; i < 4; ++i)
#pragma unroll
    for (int j = 0; j < 2; ++j) acc[i][j] = (f32x4){0.f, 0.f, 0.f, 0.f};
  gld16(Abase + (size_t)sr * HID + scol, lsA[0][0] + t * 8);
  gld16(Abase + (size_t)sr * HID + 32 + scol, lsA[0][1] + t * 8);
  gld16(Bbase + (size_t)sr * HID + scol, lsB[0][0] + t * 8);
  gld16(Bbase + (size_t)sr * HID + 32 + scol, lsB[0][1] + t * 8);
  __syncthreads();
  int cur = 0;
  for (int kt = 0; kt < HID; kt += 64) {
    int kn = kt + 64;
    if (kn < HID) {  // issue next tile's async loads; they fly during the MFMAs
      gld16(Abase + (size_t)sr * HID + kn + scol, lsA[cur ^ 1][0] + t * 8);
      gld16(Abase + (size_t)sr * HID + kn + 32 + scol, lsA[cur ^ 1][1] + t * 8);
      gld16(Bbase + (size_t)sr * HID + kn + scol, lsB[cur ^ 1][0] + t * 8);
      gld16(Bbase + (size_t)sr * HID + kn + 32 + scol, lsB[cur ^ 1][1] + t * 8);
    }
#pragma unroll
    for (int kk = 0; kk < 2; ++kk) {
      bf16x8 af[4], bfr[2];
#pragma unroll
      for (int i = 0; i < 4; ++i)
        af[i] = *(const bf16x8*)(lsA[cur][kk] + (wr * 64 + i * 16 + l15) * 32 + quad * 8);
#pragma unroll
      for (int j = 0; j < 2; ++j)
        bfr[j] = *(const bf16x8*)(lsB[cur][kk] + (wc * 32 + j * 16 + l15) * 32 + quad * 8);
#pragma unroll
      for (int i = 0; i < 4; ++i)
#pragma unroll
        for (int j = 0; j < 2; ++j)
          acc[i][j] = __builtin_amdgcn_mfma_f32_16x16x32_bf16(af[i], bfr[j], acc[i][j], 0, 0, 0);
    }
    __syncthreads();
    cur ^= 1;
  }
#pragma unroll
  for (int i = 0; i < 4; ++i) {
#pragma unroll
    for (int r = 0; r < 4; ++r) {
      int m = m0 + wr * 64 + i * 16 + quad * 4 + r;
      float bias = (m < 2048) ? bq[m] : ((m < 3072) ? bk[m - 2048] : bv[m - 3072]);
#pragma unroll
      for (int j = 0; j < 2; ++j) {
        int n = n0 + wc * 32 + j * 16 + l15;
        qkv[(size_t)m * NQ + n] = f2b(acc[i][j][r] + bias);
      }
    }
  }
}

// Flash attention: grid (h, qt8, z=4), 512 threads (8 waves x 16 q-rows = 128 q/block).
// EXACT Round-8 kernel (84.6us measured): strides 136/72/72, T14 reg-prefetch,
// ones-MFMA denominator, VGPR = 64 at the m69 occupancy cliff. Frozen — R3/R4/R9
// conflict interventions all null; the 10.17M counter is benign ~2-way aliasing
// (~3.6 counted-cycles per LDS instr), not a perf lever.
__global__ void __launch_bounds__(512) k_flash(const u16* __restrict__ qb,
                                               const u16* __restrict__ kb,
                                               const u16* __restrict__ vT,
                                               u16* __restrict__ po,
                                               float* __restrict__ pm,
                                               float* __restrict__ pl) {
  __shared__ __align__(16) u16 lsK[64 * 136];   // (s, d) row stride 272B
  __shared__ __align__(16) u16 lsV[128 * 72];   // (d, s) row stride 144B
  __shared__ __align__(16) u16 lsP[8 * 16 * 72];
  int t = threadIdx.x;
  int h = blockIdx.x, qt = blockIdx.y, z = blockIdx.z;
  int kv = h >> 1;
  int q0 = qt * 128;
  int lane = t & 63, wid = t >> 6;
  int quad = lane >> 4, l15 = lane & 15;
  int qw = q0 + wid * 16;

  // constant ones fragment (bf16 1.0) for the denominator MFMA
  union { u16 u[8]; bf16x8 v; } onesu;
#pragma unroll
  for (int e = 0; e < 8; ++e) onesu.u[e] = 0x3f80;
  bf16x8 onesf = onesu.v;

  bf16x8 qf[4];
  const u16* qrow = qb + ((size_t)h * NQ + qw + l15) * DHEAD;
#pragma unroll
  for (int kc = 0; kc < 4; ++kc) qf[kc] = *(const bf16x8*)(qrow + kc * 32 + quad * 8);
  f32x4 oacc[8];
#pragma unroll
  for (int f = 0; f < 8; ++f) oacc[f] = (f32x4){0.f, 0.f, 0.f, 0.f};
  f32x4 lacc = (f32x4){0.f, 0.f, 0.f, 0.f};
  float m_run[4];
#pragma unroll
  for (int r = 0; r < 4; ++r) m_run[r] = -1e30f;
  u16* lsPw = lsP + wid * (16 * 72);
  int Svis = CPOS + q0 + 128;
  const u16* kbase = kb + (size_t)kv * SEFF * DHEAD;
  const u16* vbase = vT + (size_t)kv * DHEAD * SEFF;

  // T14 register staging: each thread owns 2 K chunks + 2 V chunks (static coords).
  int rK = t >> 4, cK = (t & 15) * 8;  // K: 64 rows x 128 u16
  int rV = t >> 3, cV = (t & 7) * 8;   // V: 128 rows x 64 u16
  uint4 pk0, pk1, pv0, pv1;
  {
    int s0 = z * 64;
    pk0 = *(const uint4*)(kbase + (size_t)(s0 + rK) * DHEAD + cK);
    pk1 = *(const uint4*)(kbase + (size_t)(s0 + 32 + rK) * DHEAD + cK);
    pv0 = *(const uint4*)(vbase + (size_t)rV * SEFF + s0 + cV);
    pv1 = *(const uint4*)(vbase + (size_t)(64 + rV) * SEFF + s0 + cV);
  }
  for (int s0 = z * 64; s0 < Svis; s0 += 256) {
    __syncthreads();  // all waves done reading previous tile's LDS
    *(uint4*)(lsK + rK * 136 + cK) = pk0;
    *(uint4*)(lsK + (32 + rK) * 136 + cK) = pk1;
    *(uint4*)(lsV + rV * 72 + cV) = pv0;
    *(uint4*)(lsV + (64 + rV) * 72 + cV) = pv1;
    __syncthreads();  // tile visible
    int sn = s0 + 256;
    if (sn < Svis) {  // issue next tile's loads; complete under compute
      pk0 = *(const uint4*)(kbase + (size_t)(sn + rK) * DHEAD + cK);
      pk1 = *(const uint4*)(kbase + (size_t)(sn + 32 + rK) * DHEAD + cK);
      pv0 = *(const uint4*)(vbase + (size_t)rV * SEFF + sn + cV);
      pv1 = *(const uint4*)(vbase + (size_t)(64 + rV) * SEFF + sn + cV);
    }
    f32x4 sc[4];
#pragma unroll
    for (int js = 0; js < 4; ++js) {
      sc[js] = (f32x4){0.f, 0.f, 0.f, 0.f};
#pragma unroll
      for (int kc = 0; kc < 4; ++kc) {
        bf16x8 kf = *(const bf16x8*)(lsK + (js * 16 + l15) * 136 + kc * 32 + quad * 8);
        sc[js] = __builtin_amdgcn_mfma_f32_16x16x32_bf16(qf[kc], kf, sc[js], 0, 0, 0);
      }
    }
    if (s0 + 63 > CPOS + qw) {  // boundary tile for this wave: causal mask
#pragma unroll
      for (int r = 0; r < 4; ++r) {
        int lim = CPOS + qw + quad * 4 + r - s0;
#pragma unroll
        for (int js = 0; js < 4; ++js) {
          bool valid = (js * 16 + l15) <= lim;
          sc[js][r] = valid ? sc[js][r] : -1e30f;
        }
      }
    }
    float alpha[4];
#pragma unroll
    for (int r = 0; r < 4; ++r) {
      float mx = fmaxf(fmaxf(sc[0][r], sc[1][r]), fmaxf(sc[2][r], sc[3][r]));
      mx = fmaxf(mx, __shfl_xor(mx, 1, 64));
      mx = fmaxf(mx, __shfl_xor(mx, 2, 64));
      mx = fmaxf(mx, __shfl_xor(mx, 4, 64));
      mx = fmaxf(mx, __shfl_xor(mx, 8, 64));
      float mnew = fmaxf(m_run[r], mx);
      alpha[r] = __expf(m_run[r] - mnew);
      m_run[r] = mnew;
#pragma unroll
      for (int js = 0; js < 4; ++js) {
        float p = __expf(sc[js][r] - mnew);
        lsPw[(quad * 4 + r) * 72 + js * 16 + l15] = f2b_t(p);
      }
    }
#pragma unroll
    for (int f = 0; f < 8; ++f)
#pragma unroll
      for (int r = 0; r < 4; ++r) oacc[f][r] *= alpha[r];
#pragma unroll
    for (int r = 0; r < 4; ++r) lacc[r] *= alpha[r];
    bf16x8 pf[2];
#pragma unroll
    for (int ks = 0; ks < 2; ++ks)
      pf[ks] = *(const bf16x8*)(lsPw + l15 * 72 + ks * 32 + quad * 8);
#pragma unroll
    for (int f = 0; f < 8; ++f) {
#pragma unroll
      for (int ks = 0; ks < 2; ++ks) {
        bf16x8 vf = *(const bf16x8*)(lsV + (f * 16 + l15) * 72 + ks * 32 + quad * 8);
        oacc[f] = __builtin_amdgcn_mfma_f32_16x16x32_bf16(pf[ks], vf, oacc[f], 0, 0, 0);
      }
    }
#pragma unroll
    for (int ks = 0; ks < 2; ++ks)
      lacc = __builtin_amdgcn_mfma_f32_16x16x32_bf16(pf[ks], onesf, lacc, 0, 0, 0);
  }
  int p = (h * 8 + qt) * 4 + z;
#pragma unroll
  for (int r = 0; r < 4; ++r) {
    int qloc = wid * 16 + quad * 4 + r;  // 0..127
    if (l15 == 0) {
      pm[(size_t)p * 128 + qloc] = m_run[r];
      pl[(size_t)p * 128 + qloc] = lacc[r];  // running sum_s P
    }
#pragma unroll
    for (int f = 0; f < 8; ++f)
      po[(size_t)p * 16384 + qloc * 128 + f * 16 + l15] = f2b(oacc[f][r]);
  }
}

// Combine 4 S-split partials -> outT (NQ, H*D) bf16; grid (16,32):
//   by < 16 : combine (h = bx, qt = by)
//   by >= 16: Wo f32 -> bf16 streaming convert (absorbed launch)
__global__ void __launch_bounds__(256) k_combine(const u16* __restrict__ po,
                                                 const float* __restrict__ pm,
                                                 const float* __restrict__ pl,
                                                 u16* __restrict__ outT,
                                                 const float* __restrict__ Wo,
                                                 u16* __restrict__ Wob) {
  int t = threadIdx.x;
  int h = blockIdx.x;
  if (blockIdx.y >= 16) {  // Wo convert: 1,048,576 float4 over 256 blocks
    int blk = h * 16 + (blockIdx.y - 16);  // 0..255
#pragma unroll
    for (int k = 0; k < 16; ++k) {
      int i = blk * 256 + t + k * 65536;
      float4 v = ((const float4*)Wo)[i];
      *(uint2*)(Wob + (size_t)i * 4) = f4b4(v);
    }
    return;
  }
  int qt = blockIdx.y;
  int q = qt * 64 + (t >> 2);  // 0..1023
  int dq = (t & 3) * 32;
  int pb = (h * 8 + (q >> 7)) * 4;
  int ql = q & 127;
  float m0 = pm[(size_t)(pb + 0) * 128 + ql];
  float m1 = pm[(size_t)(pb + 1) * 128 + ql];
  float m2 = pm[(size_t)(pb + 2) * 128 + ql];
  float m3 = pm[(size_t)(pb + 3) * 128 + ql];
  float M = fmaxf(fmaxf(m0, m1), fmaxf(m2, m3));
  float w[4] = {__expf(m0 - M), __expf(m1 - M), __expf(m2 - M), __expf(m3 - M)};
  float L = 0.f;
#pragma unroll
  for (int zz = 0; zz < 4; ++zz) L += w[zz] * pl[(size_t)(pb + zz) * 128 + ql];
  float acc[32];
#pragma unroll
  for (int e = 0; e < 32; ++e) acc[e] = 0.f;
#pragma unroll
  for (int zz = 0; zz < 4; ++zz) {
    const u16* src = po + (size_t)(pb + zz) * 16384 + ql * 128 + dq;
#pragma unroll
    for (int j = 0; j < 4; ++j) {
      U4 v;
      v.v = *(const uint4*)(src + j * 8);
#pragma unroll
      for (int e = 0; e < 8; ++e) acc[j * 8 + e] += w[zz] * b2f(v.u[e]);
    }
  }
  float inv = 1.0f / L;
  u16* dst = outT + (size_t)q * HID + h * DHEAD + dq;
#pragma unroll
  for (int j = 0; j < 4; ++j) {
    u32 ob[4];
#pragma unroll
    for (int e = 0; e < 4; ++e)
      ob[e] = pk2(f2b(acc[j * 8 + 2 * e] * inv), f2b(acc[j * 8 + 2 * e + 1] * inv));
    *(uint4*)(dst + j * 8) = make_uint4(ob[0], ob[1], ob[2], ob[3]);
  }
}

// GEMM2: out f32 = Wob bf16 @ attn; B^T = outT. Round 10: 128x128 tiles, BK=64,
// 512 threads, dbuf gld16, grid (8,16) n-fastest (same XCD/B-panel rationale
// as GEMM1; staged bytes 262 -> 131 MB).
__global__ void __launch_bounds__(512) k_gemm_bt(const u16* __restrict__ A,
                                                 const u16* __restrict__ BT,
                                                 float* __restrict__ C) {
  __shared__ __align__(16) u16 lsA[2][2][128 * 32];
  __shared__ __align__(16) u16 lsB[2][2][128 * 32];
  int t = threadIdx.x;
  int n0 = blockIdx.x * 128, m0 = blockIdx.y * 128;
  const u16* Abase = A + (size_t)m0 * HID;
  const u16* Bbase = BT + (size_t)n0 * HID;
  int lane = t & 63, wid = t >> 6;
  int quad = lane >> 4, l15 = lane & 15;
  int wr = wid >> 2, wc = wid & 3;
  int sr = t >> 2, scol = (t & 3) * 8;
  f32x4 acc[4][2];
#pragma unroll
  for (int i = 0; i < 4; ++i)
#pragma unroll
    for (int j = 0; j < 2; ++j) acc[i][j] = (f32x4){0.f, 0.f, 0.f, 0.f};
  gld16(Abase + (size_t)sr * HID + scol, lsA[0][0] + t * 8);
  gld16(Abase + (size_t)sr * HID + 32 + scol, lsA[0][1] + t * 8);
  gld16(Bbase + (size_t)sr * HID + scol, lsB[0][0] + t * 8);
  gld16(Bbase + (size_t)sr * HID + 32 + scol, lsB[0][1] + t * 8);
  __syncthreads();
  int cur = 0;
  for (int kt = 0; kt < HID; kt += 64) {
    int kn = kt + 64;
    if (kn < HID) {
      gld16(Abase + (size_t)sr * HID + kn + scol, lsA[cur ^ 1][0] + t * 8);
      gld16(Abase + (size_t)sr * HID + kn + 32 + scol, lsA[cur ^ 1][1] + t * 8);
      gld16(Bbase + (size_t)sr * HID + kn + scol, lsB[cur ^ 1][0] + t * 8);
      gld16(Bbase + (size_t)sr * HID + kn + 32 + scol, lsB[cur ^ 1][1] + t * 8);
    }
#pragma unroll
    for (int kk = 0; kk < 2; ++kk) {
      bf16x8 af[4], bfr[2];
#pragma unroll
      for (int i = 0; i < 4; ++i)
        af[i] = *(const bf16x8*)(lsA[cur][kk] + (wr * 64 + i * 16 + l15) * 32 + quad * 8);
#pragma unroll
      for (int j = 0; j < 2; ++j)
        bfr[j] = *(const bf16x8*)(lsB[cur][kk] + (wc * 32 + j * 16 + l15) * 32 + quad * 8);
#pragma unroll
      for (int i = 0; i < 4; ++i)
#pragma unroll
        for (int j = 0; j < 2; ++j)
          acc[i][j] = __builtin_amdgcn_mfma_f32_16x16x32_bf16(af[i], bfr[j], acc[i][j], 0, 0, 0);
    }
    __syncthreads();
    cur ^= 1;
  }
#pragma unroll
  for (int i = 0; i < 4; ++i)
#pragma unroll
    for (int r = 0; r < 4; ++r) {
      int m = m0 + wr * 64 + i * 16 + quad * 4 + r;
#pragma unroll
      for (int j = 0; j < 2; ++j) {
        int n = n0 + wc * 32 + j * 16 + l15;
        C[(size_t)m * NQ + n] = acc[i][j][r];
      }
    }
}

extern "C" void kernel_launch(void* const* d_in, const int* in_sizes, int n_in,
                              void* d_out, int out_size, void* d_ws, size_t ws_size,
                              hipStream_t stream) {
  (void)in_sizes; (void)n_in; (void)out_size; (void)ws_size;
  const float* hidden = (const float*)d_in[0];
  const float* cosb = (const float*)d_in[1];
  const float* sinb = (const float*)d_in[2];
  const float* kcache = (const float*)d_in[6];
  const float* vcache = (const float*)d_in[7];
  const float* Wq = (const float*)d_in[8];
  const float* bq = (const float*)d_in[9];
  const float* Wk = (const float*)d_in[10];
  const float* bk = (const float*)d_in[11];
  const float* Wv = (const float*)d_in[12];
  const float* bv = (const float*)d_in[13];
  const float* Wo = (const float*)d_in[14];

  char* ws = (char*)d_ws;
  u16* qkv = (u16*)(ws);                    // [0 .. 8,388,608)
  u16* outT = (u16*)(ws + 8388608);         // [8,388,608 .. 12,582,912); hT overlays
  u16* hT = outT;
  u16* vT = (u16*)(ws + 12582912);          // [12,582,912 .. 23,068,672)
  u16* Wob = vT;                            // overlay: vT dead after flash
  u16* kb = (u16*)(ws + 23068672);          // [23,068,672 .. 33,554,432)
  u16* qb = (u16*)(ws + 33554432);          // [33,554,432 .. 37,748,736)
  u16* po = (u16*)(ws + 37748736);          // [37,748,736 .. 54,525,952)
  u16* Wb = po;                             // overlay: Wb dead after gemm1, po written by flash
  float* pm = (float*)(ws + 54525952);      // 256 KB
  float* pl = (float*)(ws + 54788096);      // 256 KB  (total ws 55,050,240)
  float* outb = (float*)d_out;

  k_prep_all<<<13824, 256, 0, stream>>>(hidden, hT, vcache, vT, Wq, Wk, Wv, kcache, Wb, kb);
  k_gemm_qkv<<<dim3(8, 32), 512, 0, stream>>>(Wb, hT, qkv, bq, bk, bv);
  // Wb dead from here; flash reuses its region as po
  k_rope_t<<<dim3(28, 16), 256, 0, stream>>>(qkv, cosb, sinb, qb, kb, vT);
  k_flash<<<dim3(16, 8, 4), 512, 0, stream>>>(qb, kb, vT, po, pm, pl);
  k_combine<<<dim3(16, 32), 256, 0, stream>>>(po, pm, pl, outT, Wo, Wob);
  k_gemm_bt<<<dim3(8, 16), 512, 0, stream>>>(Wob, outT, outb);
}

// Round 11
// 328.740 us; speedup vs baseline: 1.0318x; 1.0318x over previous
//
#include <hip/hip_runtime.h>

// Problem constants
#define H_HEADS 16
#define KV_HEADS 8
#define DHEAD 128
#define HID 2048
#define NQ 1024
#define SCACHE 8192
#define CPOS 4096
#define SEFF 5120

typedef __attribute__((ext_vector_type(8))) __bf16 bf16x8;
typedef __attribute__((ext_vector_type(4))) float f32x4;
typedef unsigned short u16;
typedef unsigned int u32;

__device__ __forceinline__ u16 f2b(float f) {  // f32 -> bf16 bits, RNE
  u32 u = __float_as_uint(f);
  u += 0x7fffu + ((u >> 16) & 1u);
  return (u16)(u >> 16);
}
__device__ __forceinline__ u16 f2b_t(float f) {  // truncating (for P only)
  return (u16)(__float_as_uint(f) >> 16);
}
__device__ __forceinline__ float b2f(u16 b) { return __uint_as_float(((u32)b) << 16); }
__device__ __forceinline__ u32 pk2(u16 a, u16 b) { return (u32)a | ((u32)b << 16); }
__device__ __forceinline__ uint2 f4b4(float4 v) {
  uint2 o;
  o.x = pk2(f2b(v.x), f2b(v.y));
  o.y = pk2(f2b(v.z), f2b(v.w));
  return o;
}

// async global->LDS, 16B per lane (gfx950). LDS dest must be wave-uniform base
// + lane*16 — callers keep the LDS layout linear in lane order.
__device__ __forceinline__ void gld16(const u16* g, u16* l) {
  __builtin_amdgcn_global_load_lds((const __attribute__((address_space(1))) void*)g,
                                   (__attribute__((address_space(3))) void*)l, 16, 0, 0);
}

union U4 { uint4 v; u16 u[8]; };

// Merged prep kernel (R8, measured in the 328.3us best run):
//   bx <  512           : transpose_h block  (c0=(bx&31)*64, q0=(bx>>5)*64)
//   bx < 1536           : prep_vT32 block    (pb=bx-512: s0=(pb&127)*32, kv=pb>>7)
//   else                : streaming converts (W -> Wb, kcache -> kb)
__global__ void __launch_bounds__(256) k_prep_all(
    const float* __restrict__ hid, u16* __restrict__ hT,
    const float* __restrict__ vc, u16* __restrict__ vT,
    const float* __restrict__ Wq, const float* __restrict__ Wk,
    const float* __restrict__ Wv, const float* __restrict__ kc,
    u16* __restrict__ Wb, u16* __restrict__ kb) {
  __shared__ __align__(16) float ls[64 * 68];  // 17.4 KB; prep_vT32 uses 32*132 <= this
  int t = threadIdx.x;
  int bx = blockIdx.x;
  if (bx < 512) {  // ---- transpose_h ----
    int c0 = (bx & 31) * 64, q0 = (bx >> 5) * 64;
#pragma unroll
    for (int it = 0; it < 4; ++it) {
      int c = it * 256 + t;
      int row = c >> 4, ch = c & 15;
      *(float4*)(ls + row * 68 + ch * 4) =
          *(const float4*)(hid + (size_t)(c0 + row) * NQ + q0 + ch * 4);
    }
    __syncthreads();
    int ql = t & 63, cch = t >> 6;
    u32 ob[8];
#pragma unroll
    for (int j = 0; j < 8; ++j)
      ob[j] = pk2(f2b(ls[(cch * 16 + 2 * j) * 68 + ql]), f2b(ls[(cch * 16 + 2 * j + 1) * 68 + ql]));
    uint4* dst = (uint4*)(hT + (size_t)(q0 + ql) * HID + c0 + cch * 16);
    dst[0] = make_uint4(ob[0], ob[1], ob[2], ob[3]);
    dst[1] = make_uint4(ob[4], ob[5], ob[6], ob[7]);
    return;
  }
  if (bx < 1536) {  // ---- prep_vT, 32 s-rows per block ----
    int pb = bx - 512;
    int s0 = (pb & 127) * 32;
    int kv = pb >> 7;
#pragma unroll
    for (int it = 0; it < 4; ++it) {  // 32 rows x 128 cols = 1024 float4
      int c = it * 256 + t;
      int row = c >> 5, ch = c & 31;
      *(float4*)(ls + row * 132 + ch * 4) =
          *(const float4*)(vc + ((size_t)kv * SCACHE + s0 + row) * DHEAD + ch * 4);
    }
    __syncthreads();
    int d = t >> 1, half = t & 1;  // each thread: 16 s-values of one d-row
    u32 ob[8];
#pragma unroll
    for (int j = 0; j < 8; ++j)
      ob[j] = pk2(f2b(ls[(half * 16 + 2 * j) * 132 + d]), f2b(ls[(half * 16 + 2 * j + 1) * 132 + d]));
    uint4* dst = (uint4*)(vT + ((size_t)kv * DHEAD + d) * SEFF + s0 + half * 16);
    dst[0] = make_uint4(ob[0], ob[1], ob[2], ob[3]);
    dst[1] = make_uint4(ob[4], ob[5], ob[6], ob[7]);
    return;
  }
  // ---- streaming converts ----
  int i = (bx - 1536) * 256 + t;
  if (i < 2097152) {  // Wq|Wk|Wv f32 -> Wb bf16
    const float* src;
    int off;
    if (i < 1048576) { src = Wq; off = i; }
    else if (i < 1572864) { src = Wk; off = i - 1048576; }
    else { src = Wv; off = i - 1572864; }
    float4 v = ((const float4*)src)[off];
    *(uint2*)(Wb + (size_t)i * 4) = f4b4(v);
  } else {  // kcache f32 -> kb bf16
    int j = i - 2097152;
    int kvi = j >> 17;
    int rem = j & 131071;
    float4 v = *(const float4*)(kc + (size_t)kvi * SCACHE * DHEAD + (size_t)rem * 4);
    *(uint2*)(kb + (size_t)kvi * SEFF * DHEAD + (size_t)rem * 4) = f4b4(v);
  }
}

// Transposing RoPE + V-new copy:
//   hh < 16 : qkv q-part -> qb (h,q,d) [scaled]
//   hh < 24 : qkv k-part -> kb rows CPOS+q
//   hh >= 24: qkv v-part rows (d-major) -> vT s in [CPOS, SEFF), 64 blocks
__global__ void __launch_bounds__(256) k_rope_t(const u16* __restrict__ qkv,
                                                const float* __restrict__ cosb,
                                                const float* __restrict__ sinb,
                                                u16* __restrict__ qb,
                                                u16* __restrict__ kb,
                                                u16* __restrict__ vT) {
  __shared__ __align__(16) u16 ls[64 * 136];  // [q][d]
  int t = threadIdx.x;
  int hh = blockIdx.x;
  if (hh >= 24) {  // V-copy: 131072 uint4 chunks over 64 blocks x 8 iters
    int blk = (hh - 24) * 16 + blockIdx.y;  // 0..63
#pragma unroll
    for (int it = 0; it < 8; ++it) {
      int i = blk * 2048 + it * 256 + t;
      int row = i >> 7, ch = i & 127;
      *(uint4*)(vT + (size_t)row * SEFF + CPOS + ch * 8) =
          *(const uint4*)(qkv + (size_t)(3072 + row) * NQ + ch * 8);
    }
    return;
  }
  int q0 = blockIdx.y * 64;
  bool isq = hh < 16;
  int rowbase = isq ? hh * DHEAD : HID + (hh - 16) * DHEAD;
#pragma unroll
  for (int it = 0; it < 4; ++it) {
    int c = it * 256 + t;
    int d = c >> 3, qc = (c & 7) * 8;
    U4 v;
    v.v = *(const uint4*)(qkv + (size_t)(rowbase + d) * NQ + q0 + qc);
#pragma unroll
    for (int e = 0; e < 8; ++e) ls[(qc + e) * 136 + d] = v.u[e];
  }
  __syncthreads();
  int ql = t & 63, hf = t >> 6;
  int q = q0 + ql;
  float scale = isq ? 0.08838834764831845f : 1.0f;
  u16* dst = isq ? (qb + ((size_t)hh * NQ + q) * DHEAD)
                 : (kb + ((size_t)(hh - 16) * SEFF + CPOS + q) * DHEAD);
#pragma unroll
  for (int g = 0; g < 4; ++g) {
    int d0 = hf * 32 + g * 8;
    U4 x, y;
    x.v = *(uint4*)(ls + ql * 136 + d0);
    y.v = *(uint4*)(ls + ql * 136 + (d0 ^ 64));
    float4 ca = *(const float4*)(cosb + (size_t)q * DHEAD + d0);
    float4 cb = *(const float4*)(cosb + (size_t)q * DHEAD + d0 + 4);
    float4 sa = *(const float4*)(sinb + (size_t)q * DHEAD + d0);
    float4 sb = *(const float4*)(sinb + (size_t)q * DHEAD + d0 + 4);
    float cs[8] = {ca.x, ca.y, ca.z, ca.w, cb.x, cb.y, cb.z, cb.w};
    float sn[8] = {sa.x, sa.y, sa.z, sa.w, sb.x, sb.y, sb.z, sb.w};
    float sgn = (d0 < 64) ? -1.0f : 1.0f;
    u32 ob[4];
#pragma unroll
    for (int e = 0; e < 4; ++e) {
      float r0 = (b2f(x.u[2 * e]) * cs[2 * e] + sgn * b2f(y.u[2 * e]) * sn[2 * e]) * scale;
      float r1 = (b2f(x.u[2 * e + 1]) * cs[2 * e + 1] + sgn * b2f(y.u[2 * e + 1]) * sn[2 * e + 1]) * scale;
      ob[e] = pk2(f2b(r0), f2b(r1));
    }
    *(uint4*)(dst + d0) = make_uint4(ob[0], ob[1], ob[2], ob[3]);
  }
}

// GEMM1: qkv = Wb @ hT^T + bias. 64x64 tiles, BK=64, grid (64,16)=1024
// -> 4 blocks/CU, 32 barriers. Measured optimum (R8 = 328.3us; 128^2 tiles
// at 1 block/CU regressed in R10 — occupancy beats panel-traffic here).
// A-panel XCD locality is already present: the 16 blocks sharing bx (A-panel)
// all map to XCD bx%8.
__global__ void __launch_bounds__(256) k_gemm_qkv(
    const u16* __restrict__ Wb, const u16* __restrict__ hT, u16* __restrict__ qkv,
    const float* __restrict__ bq, const float* __restrict__ bk, const float* __restrict__ bv) {
  __shared__ __align__(16) u16 lsA[2][2][64 * 32];  // [dbuf][khalf][row*32+col]
  __shared__ __align__(16) u16 lsB[2][2][64 * 32];
  int t = threadIdx.x;
  int m0 = blockIdx.x * 64, n0 = blockIdx.y * 64;
  const u16* Abase = Wb + (size_t)m0 * HID;
  const u16* Bbase = hT + (size_t)n0 * HID;
  int lane = t & 63, wid = t >> 6;
  int quad = lane >> 4, l15 = lane & 15;
  int wr = wid >> 1, wc = wid & 1;
  int sr = t >> 2, scol = (t & 3) * 8;
  f32x4 acc[2][2];
#pragma unroll
  for (int i = 0; i < 2; ++i)
#pragma unroll
    for (int j = 0; j < 2; ++j) acc[i][j] = (f32x4){0.f, 0.f, 0.f, 0.f};
  gld16(Abase + (size_t)sr * HID + scol, lsA[0][0] + t * 8);
  gld16(Abase + (size_t)sr * HID + 32 + scol, lsA[0][1] + t * 8);
  gld16(Bbase + (size_t)sr * HID + scol, lsB[0][0] + t * 8);
  gld16(Bbase + (size_t)sr * HID + 32 + scol, lsB[0][1] + t * 8);
  __syncthreads();
  int cur = 0;
  for (int kt = 0; kt < HID; kt += 64) {
    int kn = kt + 64;
    if (kn < HID) {
      gld16(Abase + (size_t)sr * HID + kn + scol, lsA[cur ^ 1][0] + t * 8);
      gld16(Abase + (size_t)sr * HID + kn + 32 + scol, lsA[cur ^ 1][1] + t * 8);
      gld16(Bbase + (size_t)sr * HID + kn + scol, lsB[cur ^ 1][0] + t * 8);
      gld16(Bbase + (size_t)sr * HID + kn + 32 + scol, lsB[cur ^ 1][1] + t * 8);
    }
#pragma unroll
    for (int kk = 0; kk < 2; ++kk) {
      bf16x8 af[2], bfr[2];
#pragma unroll
      for (int i = 0; i < 2; ++i)
        af[i] = *(const bf16x8*)(lsA[cur][kk] + (wr * 32 + i * 16 + l15) * 32 + quad * 8);
#pragma unroll
      for (int j = 0; j < 2; ++j)
        bfr[j] = *(const bf16x8*)(lsB[cur][kk] + (wc * 32 + j * 16 + l15) * 32 + quad * 8);
#pragma unroll
      for (int i = 0; i < 2; ++i)
#pragma unroll
        for (int j = 0; j < 2; ++j)
          acc[i][j] = __builtin_amdgcn_mfma_f32_16x16x32_bf16(af[i], bfr[j], acc[i][j], 0, 0, 0);
    }
    __syncthreads();
    cur ^= 1;
  }
#pragma unroll
  for (int i = 0; i < 2; ++i) {
#pragma unroll
    for (int r = 0; r < 4; ++r) {
      int m = m0 + wr * 32 + i * 16 + quad * 4 + r;
      float bias = (m < 2048) ? bq[m] : ((m < 3072) ? bk[m - 2048] : bv[m - 3072]);
#pragma unroll
      for (int j = 0; j < 2; ++j) {
        int n = n0 + wc * 32 + j * 16 + l15;
        qkv[(size_t)m * NQ + n] = f2b(acc[i][j][r] + bias);
      }
    }
  }
}

// Flash attention: grid (h, qt8, z=4), 512 threads (8 waves x 16 q-rows = 128 q/block).
// EXACT Round-8 kernel (84.6us measured): strides 136/72/72, T14 reg-prefetch,
// ones-MFMA denominator, VGPR = 64 at the m69 occupancy cliff. Frozen — R3/R4/R9
// conflict interventions all null; the 10.17M counter is benign ~2-way aliasing,
// not a perf lever.
__global__ void __launch_bounds__(512) k_flash(const u16* __restrict__ qb,
                                               const u16* __restrict__ kb,
                                               const u16* __restrict__ vT,
                                               u16* __restrict__ po,
                                               float* __restrict__ pm,
                                               float* __restrict__ pl) {
  __shared__ __align__(16) u16 lsK[64 * 136];   // (s, d) row stride 272B
  __shared__ __align__(16) u16 lsV[128 * 72];   // (d, s) row stride 144B
  __shared__ __align__(16) u16 lsP[8 * 16 * 72];
  int t = threadIdx.x;
  int h = blockIdx.x, qt = blockIdx.y, z = blockIdx.z;
  int kv = h >> 1;
  int q0 = qt * 128;
  int lane = t & 63, wid = t >> 6;
  int quad = lane >> 4, l15 = lane & 15;
  int qw = q0 + wid * 16;

  // constant ones fragment (bf16 1.0) for the denominator MFMA
  union { u16 u[8]; bf16x8 v; } onesu;
#pragma unroll
  for (int e = 0; e < 8; ++e) onesu.u[e] = 0x3f80;
  bf16x8 onesf = onesu.v;

  bf16x8 qf[4];
  const u16* qrow = qb + ((size_t)h * NQ + qw + l15) * DHEAD;
#pragma unroll
  for (int kc = 0; kc < 4; ++kc) qf[kc] = *(const bf16x8*)(qrow + kc * 32 + quad * 8);
  f32x4 oacc[8];
#pragma unroll
  for (int f = 0; f < 8; ++f) oacc[f] = (f32x4){0.f, 0.f, 0.f, 0.f};
  f32x4 lacc = (f32x4){0.f, 0.f, 0.f, 0.f};
  float m_run[4];
#pragma unroll
  for (int r = 0; r < 4; ++r) m_run[r] = -1e30f;
  u16* lsPw = lsP + wid * (16 * 72);
  int Svis = CPOS + q0 + 128;
  const u16* kbase = kb + (size_t)kv * SEFF * DHEAD;
  const u16* vbase = vT + (size_t)kv * DHEAD * SEFF;

  // T14 register staging: each thread owns 2 K chunks + 2 V chunks (static coords).
  int rK = t >> 4, cK = (t & 15) * 8;  // K: 64 rows x 128 u16
  int rV = t >> 3, cV = (t & 7) * 8;   // V: 128 rows x 64 u16
  uint4 pk0, pk1, pv0, pv1;
  {
    int s0 = z * 64;
    pk0 = *(const uint4*)(kbase + (size_t)(s0 + rK) * DHEAD + cK);
    pk1 = *(const uint4*)(kbase + (size_t)(s0 + 32 + rK) * DHEAD + cK);
    pv0 = *(const uint4*)(vbase + (size_t)rV * SEFF + s0 + cV);
    pv1 = *(const uint4*)(vbase + (size_t)(64 + rV) * SEFF + s0 + cV);
  }
  for (int s0 = z * 64; s0 < Svis; s0 += 256) {
    __syncthreads();  // all waves done reading previous tile's LDS
    *(uint4*)(lsK + rK * 136 + cK) = pk0;
    *(uint4*)(lsK + (32 + rK) * 136 + cK) = pk1;
    *(uint4*)(lsV + rV * 72 + cV) = pv0;
    *(uint4*)(lsV + (64 + rV) * 72 + cV) = pv1;
    __syncthreads();  // tile visible
    int sn = s0 + 256;
    if (sn < Svis) {  // issue next tile's loads; complete under compute
      pk0 = *(const uint4*)(kbase + (size_t)(sn + rK) * DHEAD + cK);
      pk1 = *(const uint4*)(kbase + (size_t)(sn + 32 + rK) * DHEAD + cK);
      pv0 = *(const uint4*)(vbase + (size_t)rV * SEFF + sn + cV);
      pv1 = *(const uint4*)(vbase + (size_t)(64 + rV) * SEFF + sn + cV);
    }
    f32x4 sc[4];
#pragma unroll
    for (int js = 0; js < 4; ++js) {
      sc[js] = (f32x4){0.f, 0.f, 0.f, 0.f};
#pragma unroll
      for (int kc = 0; kc < 4; ++kc) {
        bf16x8 kf = *(const bf16x8*)(lsK + (js * 16 + l15) * 136 + kc * 32 + quad * 8);
        sc[js] = __builtin_amdgcn_mfma_f32_16x16x32_bf16(qf[kc], kf, sc[js], 0, 0, 0);
      }
    }
    if (s0 + 63 > CPOS + qw) {  // boundary tile for this wave: causal mask
#pragma unroll
      for (int r = 0; r < 4; ++r) {
        int lim = CPOS + qw + quad * 4 + r - s0;
#pragma unroll
        for (int js = 0; js < 4; ++js) {
          bool valid = (js * 16 + l15) <= lim;
          sc[js][r] = valid ? sc[js][r] : -1e30f;
        }
      }
    }
    float alpha[4];
#pragma unroll
    for (int r = 0; r < 4; ++r) {
      float mx = fmaxf(fmaxf(sc[0][r], sc[1][r]), fmaxf(sc[2][r], sc[3][r]));
      mx = fmaxf(mx, __shfl_xor(mx, 1, 64));
      mx = fmaxf(mx, __shfl_xor(mx, 2, 64));
      mx = fmaxf(mx, __shfl_xor(mx, 4, 64));
      mx = fmaxf(mx, __shfl_xor(mx, 8, 64));
      float mnew = fmaxf(m_run[r], mx);
      alpha[r] = __expf(m_run[r] - mnew);
      m_run[r] = mnew;
#pragma unroll
      for (int js = 0; js < 4; ++js) {
        float p = __expf(sc[js][r] - mnew);
        lsPw[(quad * 4 + r) * 72 + js * 16 + l15] = f2b_t(p);
      }
    }
#pragma unroll
    for (int f = 0; f < 8; ++f)
#pragma unroll
      for (int r = 0; r < 4; ++r) oacc[f][r] *= alpha[r];
#pragma unroll
    for (int r = 0; r < 4; ++r) lacc[r] *= alpha[r];
    bf16x8 pf[2];
#pragma unroll
    for (int ks = 0; ks < 2; ++ks)
      pf[ks] = *(const bf16x8*)(lsPw + l15 * 72 + ks * 32 + quad * 8);
#pragma unroll
    for (int f = 0; f < 8; ++f) {
#pragma unroll
      for (int ks = 0; ks < 2; ++ks) {
        bf16x8 vf = *(const bf16x8*)(lsV + (f * 16 + l15) * 72 + ks * 32 + quad * 8);
        oacc[f] = __builtin_amdgcn_mfma_f32_16x16x32_bf16(pf[ks], vf, oacc[f], 0, 0, 0);
      }
    }
#pragma unroll
    for (int ks = 0; ks < 2; ++ks)
      lacc = __builtin_amdgcn_mfma_f32_16x16x32_bf16(pf[ks], onesf, lacc, 0, 0, 0);
  }
  int p = (h * 8 + qt) * 4 + z;
#pragma unroll
  for (int r = 0; r < 4; ++r) {
    int qloc = wid * 16 + quad * 4 + r;  // 0..127
    if (l15 == 0) {
      pm[(size_t)p * 128 + qloc] = m_run[r];
      pl[(size_t)p * 128 + qloc] = lacc[r];  // running sum_s P
    }
#pragma unroll
    for (int f = 0; f < 8; ++f)
      po[(size_t)p * 16384 + qloc * 128 + f * 16 + l15] = f2b(oacc[f][r]);
  }
}

// Combine 4 S-split partials -> outT (NQ, H*D) bf16; grid (16,32):
//   by < 16 : combine (h = bx, qt = by)
//   by >= 16: Wo f32 -> bf16 streaming convert (absorbed launch)
__global__ void __launch_bounds__(256) k_combine(const u16* __restrict__ po,
                                                 const float* __restrict__ pm,
                                                 const float* __restrict__ pl,
                                                 u16* __restrict__ outT,
                                                 const float* __restrict__ Wo,
                                                 u16* __restrict__ Wob) {
  int t = threadIdx.x;
  int h = blockIdx.x;
  if (blockIdx.y >= 16) {  // Wo convert: 1,048,576 float4 over 256 blocks
    int blk = h * 16 + (blockIdx.y - 16);  // 0..255
#pragma unroll
    for (int k = 0; k < 16; ++k) {
      int i = blk * 256 + t + k * 65536;
      float4 v = ((const float4*)Wo)[i];
      *(uint2*)(Wob + (size_t)i * 4) = f4b4(v);
    }
    return;
  }
  int qt = blockIdx.y;
  int q = qt * 64 + (t >> 2);  // 0..1023
  int dq = (t & 3) * 32;
  int pb = (h * 8 + (q >> 7)) * 4;
  int ql = q & 127;
  float m0 = pm[(size_t)(pb + 0) * 128 + ql];
  float m1 = pm[(size_t)(pb + 1) * 128 + ql];
  float m2 = pm[(size_t)(pb + 2) * 128 + ql];
  float m3 = pm[(size_t)(pb + 3) * 128 + ql];
  float M = fmaxf(fmaxf(m0, m1), fmaxf(m2, m3));
  float w[4] = {__expf(m0 - M), __expf(m1 - M), __expf(m2 - M), __expf(m3 - M)};
  float L = 0.f;
#pragma unroll
  for (int zz = 0; zz < 4; ++zz) L += w[zz] * pl[(size_t)(pb + zz) * 128 + ql];
  float acc[32];
#pragma unroll
  for (int e = 0; e < 32; ++e) acc[e] = 0.f;
#pragma unroll
  for (int zz = 0; zz < 4; ++zz) {
    const u16* src = po + (size_t)(pb + zz) * 16384 + ql * 128 + dq;
#pragma unroll
    for (int j = 0; j < 4; ++j) {
      U4 v;
      v.v = *(const uint4*)(src + j * 8);
#pragma unroll
      for (int e = 0; e < 8; ++e) acc[j * 8 + e] += w[zz] * b2f(v.u[e]);
    }
  }
  float inv = 1.0f / L;
  u16* dst = outT + (size_t)q * HID + h * DHEAD + dq;
#pragma unroll
  for (int j = 0; j < 4; ++j) {
    u32 ob[4];
#pragma unroll
    for (int e = 0; e < 4; ++e)
      ob[e] = pk2(f2b(acc[j * 8 + 2 * e] * inv), f2b(acc[j * 8 + 2 * e + 1] * inv));
    *(uint4*)(dst + j * 8) = make_uint4(ob[0], ob[1], ob[2], ob[3]);
  }
}

// GEMM2: out f32 = Wob bf16 @ attn; B^T = outT. 64x64 tiles, BK=64,
// dbuf gld16, grid (32,16)=512 (R8 measured optimum).
__global__ void __launch_bounds__(256) k_gemm_bt(const u16* __restrict__ A,
                                                 const u16* __restrict__ BT,
                                                 float* __restrict__ C) {
  __shared__ __align__(16) u16 lsA[2][2][64 * 32];
  __shared__ __align__(16) u16 lsB[2][2][64 * 32];
  int t = threadIdx.x;
  int m0 = blockIdx.x * 64, n0 = blockIdx.y * 64;
  const u16* Abase = A + (size_t)m0 * HID;
  const u16* Bbase = BT + (size_t)n0 * HID;
  int lane = t & 63, wid = t >> 6;
  int quad = lane >> 4, l15 = lane & 15;
  int wr = wid >> 1, wc = wid & 1;
  int sr = t >> 2, scol = (t & 3) * 8;
  f32x4 acc[2][2];
#pragma unroll
  for (int i = 0; i < 2; ++i)
#pragma unroll
    for (int j = 0; j < 2; ++j) acc[i][j] = (f32x4){0.f, 0.f, 0.f, 0.f};
  gld16(Abase + (size_t)sr * HID + scol, lsA[0][0] + t * 8);
  gld16(Abase + (size_t)sr * HID + 32 + scol, lsA[0][1] + t * 8);
  gld16(Bbase + (size_t)sr * HID + scol, lsB[0][0] + t * 8);
  gld16(Bbase + (size_t)sr * HID + 32 + scol, lsB[0][1] + t * 8);
  __syncthreads();
  int cur = 0;
  for (int kt = 0; kt < HID; kt += 64) {
    int kn = kt + 64;
    if (kn < HID) {
      gld16(Abase + (size_t)sr * HID + kn + scol, lsA[cur ^ 1][0] + t * 8);
      gld16(Abase + (size_t)sr * HID + kn + 32 + scol, lsA[cur ^ 1][1] + t * 8);
      gld16(Bbase + (size_t)sr * HID + kn + scol, lsB[cur ^ 1][0] + t * 8);
      gld16(Bbase + (size_t)sr * HID + kn + 32 + scol, lsB[cur ^ 1][1] + t * 8);
    }
#pragma unroll
    for (int kk = 0; kk < 2; ++kk) {
      bf16x8 af[2], bfr[2];
#pragma unroll
      for (int i = 0; i < 2; ++i)
        af[i] = *(const bf16x8*)(lsA[cur][kk] + (wr * 32 + i * 16 + l15) * 32 + quad * 8);
#pragma unroll
      for (int j = 0; j < 2; ++j)
        bfr[j] = *(const bf16x8*)(lsB[cur][kk] + (wc * 32 + j * 16 + l15) * 32 + quad * 8);
#pragma unroll
      for (int i = 0; i < 2; ++i)
#pragma unroll
        for (int j = 0; j < 2; ++j)
          acc[i][j] = __builtin_amdgcn_mfma_f32_16x16x32_bf16(af[i], bfr[j], acc[i][j], 0, 0, 0);
    }
    __syncthreads();
    cur ^= 1;
  }
#pragma unroll
  for (int i = 0; i < 2; ++i)
#pragma unroll
    for (int r = 0; r < 4; ++r) {
      int m = m0 + wr * 32 + i * 16 + quad * 4 + r;
#pragma unroll
      for (int j = 0; j < 2; ++j) {
        int n = n0 + wc * 32 + j * 16 + l15;
        C[(size_t)m * NQ + n] = acc[i][j][r];
      }
    }
}

extern "C" void kernel_launch(void* const* d_in, const int* in_sizes, int n_in,
                              void* d_out, int out_size, void* d_ws, size_t ws_size,
                              hipStream_t stream) {
  (void)in_sizes; (void)n_in; (void)out_size; (void)ws_size;
  const float* hidden = (const float*)d_in[0];
  const float* cosb = (const float*)d_in[1];
  const float* sinb = (const float*)d_in[2];
  const float* kcache = (const float*)d_in[6];
  const float* vcache = (const float*)d_in[7];
  const float* Wq = (const float*)d_in[8];
  const float* bq = (const float*)d_in[9];
  const float* Wk = (const float*)d_in[10];
  const float* bk = (const float*)d_in[11];
  const float* Wv = (const float*)d_in[12];
  const float* bv = (const float*)d_in[13];
  const float* Wo = (const float*)d_in[14];

  char* ws = (char*)d_ws;
  u16* qkv = (u16*)(ws);                    // [0 .. 8,388,608)
  u16* outT = (u16*)(ws + 8388608);         // [8,388,608 .. 12,582,912); hT overlays
  u16* hT = outT;
  u16* vT = (u16*)(ws + 12582912);          // [12,582,912 .. 23,068,672)
  u16* Wob = vT;                            // overlay: vT dead after flash
  u16* kb = (u16*)(ws + 23068672);          // [23,068,672 .. 33,554,432)
  u16* qb = (u16*)(ws + 33554432);          // [33,554,432 .. 37,748,736)
  u16* po = (u16*)(ws + 37748736);          // [37,748,736 .. 54,525,952)
  u16* Wb = po;                             // overlay: Wb dead after gemm1, po written by flash
  float* pm = (float*)(ws + 54525952);      // 256 KB
  float* pl = (float*)(ws + 54788096);      // 256 KB  (total ws 55,050,240)
  float* outb = (float*)d_out;

  k_prep_all<<<13824, 256, 0, stream>>>(hidden, hT, vcache, vT, Wq, Wk, Wv, kcache, Wb, kb);
  k_gemm_qkv<<<dim3(64, 16), 256, 0, stream>>>(Wb, hT, qkv, bq, bk, bv);
  // Wb dead from here; flash reuses its region as po
  k_rope_t<<<dim3(28, 16), 256, 0, stream>>>(qkv, cosb, sinb, qb, kb, vT);
  k_flash<<<dim3(16, 8, 4), 512, 0, stream>>>(qb, kb, vT, po, pm, pl);
  k_combine<<<dim3(16, 32), 256, 0, stream>>>(po, pm, pl, outT, Wo, Wob);
  k_gemm_bt<<<dim3(32, 16), 256, 0, stream>>>(Wob, outT, outb);
}

// Round 12
// 328.218 us; speedup vs baseline: 1.0334x; 1.0016x over previous
//
#include <hip/hip_runtime.h>

// Problem constants
#define H_HEADS 16
#define KV_HEADS 8
#define DHEAD 128
#define HID 2048
#define NQ 1024
#define SCACHE 8192
#define CPOS 4096
#define SEFF 5120

typedef __attribute__((ext_vector_type(8))) __bf16 bf16x8;
typedef __attribute__((ext_vector_type(4))) float f32x4;
typedef unsigned short u16;
typedef unsigned int u32;

__device__ __forceinline__ u16 f2b(float f) {  // f32 -> bf16 bits, RNE
  u32 u = __float_as_uint(f);
  u += 0x7fffu + ((u >> 16) & 1u);
  return (u16)(u >> 16);
}
__device__ __forceinline__ u16 f2b_t(float f) {  // truncating (for P only)
  return (u16)(__float_as_uint(f) >> 16);
}
__device__ __forceinline__ float b2f(u16 b) { return __uint_as_float(((u32)b) << 16); }
__device__ __forceinline__ u32 pk2(u16 a, u16 b) { return (u32)a | ((u32)b << 16); }
__device__ __forceinline__ uint2 f4b4(float4 v) {
  uint2 o;
  o.x = pk2(f2b(v.x), f2b(v.y));
  o.y = pk2(f2b(v.z), f2b(v.w));
  return o;
}

// async global->LDS, 16B per lane (gfx950). LDS dest must be wave-uniform base
// + lane*16 — callers keep the LDS layout linear in lane order.
__device__ __forceinline__ void gld16(const u16* g, u16* l) {
  __builtin_amdgcn_global_load_lds((const __attribute__((address_space(1))) void*)g,
                                   (__attribute__((address_space(3))) void*)l, 16, 0, 0);
}

union U4 { uint4 v; u16 u[8]; };

// Merged prep kernel (R8, measured in the 328.3us best run):
//   bx <  512           : transpose_h block  (c0=(bx&31)*64, q0=(bx>>5)*64)
//   bx < 1536           : prep_vT32 block    (pb=bx-512: s0=(pb&127)*32, kv=pb>>7)
//   else                : streaming converts (W -> Wb, kcache -> kb)
__global__ void __launch_bounds__(256) k_prep_all(
    const float* __restrict__ hid, u16* __restrict__ hT,
    const float* __restrict__ vc, u16* __restrict__ vT,
    const float* __restrict__ Wq, const float* __restrict__ Wk,
    const float* __restrict__ Wv, const float* __restrict__ kc,
    u16* __restrict__ Wb, u16* __restrict__ kb) {
  __shared__ __align__(16) float ls[64 * 68];  // 17.4 KB; prep_vT32 uses 32*132 <= this
  int t = threadIdx.x;
  int bx = blockIdx.x;
  if (bx < 512) {  // ---- transpose_h ----
    int c0 = (bx & 31) * 64, q0 = (bx >> 5) * 64;
#pragma unroll
    for (int it = 0; it < 4; ++it) {
      int c = it * 256 + t;
      int row = c >> 4, ch = c & 15;
      *(float4*)(ls + row * 68 + ch * 4) =
          *(const float4*)(hid + (size_t)(c0 + row) * NQ + q0 + ch * 4);
    }
    __syncthreads();
    int ql = t & 63, cch = t >> 6;
    u32 ob[8];
#pragma unroll
    for (int j = 0; j < 8; ++j)
      ob[j] = pk2(f2b(ls[(cch * 16 + 2 * j) * 68 + ql]), f2b(ls[(cch * 16 + 2 * j + 1) * 68 + ql]));
    uint4* dst = (uint4*)(hT + (size_t)(q0 + ql) * HID + c0 + cch * 16);
    dst[0] = make_uint4(ob[0], ob[1], ob[2], ob[3]);
    dst[1] = make_uint4(ob[4], ob[5], ob[6], ob[7]);
    return;
  }
  if (bx < 1536) {  // ---- prep_vT, 32 s-rows per block ----
    int pb = bx - 512;
    int s0 = (pb & 127) * 32;
    int kv = pb >> 7;
#pragma unroll
    for (int it = 0; it < 4; ++it) {  // 32 rows x 128 cols = 1024 float4
      int c = it * 256 + t;
      int row = c >> 5, ch = c & 31;
      *(float4*)(ls + row * 132 + ch * 4) =
          *(const float4*)(vc + ((size_t)kv * SCACHE + s0 + row) * DHEAD + ch * 4);
    }
    __syncthreads();
    int d = t >> 1, half = t & 1;  // each thread: 16 s-values of one d-row
    u32 ob[8];
#pragma unroll
    for (int j = 0; j < 8; ++j)
      ob[j] = pk2(f2b(ls[(half * 16 + 2 * j) * 132 + d]), f2b(ls[(half * 16 + 2 * j + 1) * 132 + d]));
    uint4* dst = (uint4*)(vT + ((size_t)kv * DHEAD + d) * SEFF + s0 + half * 16);
    dst[0] = make_uint4(ob[0], ob[1], ob[2], ob[3]);
    dst[1] = make_uint4(ob[4], ob[5], ob[6], ob[7]);
    return;
  }
  // ---- streaming converts ----
  int i = (bx - 1536) * 256 + t;
  if (i < 2097152) {  // Wq|Wk|Wv f32 -> Wb bf16
    const float* src;
    int off;
    if (i < 1048576) { src = Wq; off = i; }
    else if (i < 1572864) { src = Wk; off = i - 1048576; }
    else { src = Wv; off = i - 1572864; }
    float4 v = ((const float4*)src)[off];
    *(uint2*)(Wb + (size_t)i * 4) = f4b4(v);
  } else {  // kcache f32 -> kb bf16
    int j = i - 2097152;
    int kvi = j >> 17;
    int rem = j & 131071;
    float4 v = *(const float4*)(kc + (size_t)kvi * SCACHE * DHEAD + (size_t)rem * 4);
    *(uint2*)(kb + (size_t)kvi * SEFF * DHEAD + (size_t)rem * 4) = f4b4(v);
  }
}

// Transposing RoPE + V-new copy:
//   hh < 16 : qkv q-part -> qb (h,q,d) [scaled]
//   hh < 24 : qkv k-part -> kb rows CPOS+q
//   hh >= 24: qkv v-part rows (d-major) -> vT s in [CPOS, SEFF), 64 blocks
__global__ void __launch_bounds__(256) k_rope_t(const u16* __restrict__ qkv,
                                                const float* __restrict__ cosb,
                                                const float* __restrict__ sinb,
                                                u16* __restrict__ qb,
                                                u16* __restrict__ kb,
                                                u16* __restrict__ vT) {
  __shared__ __align__(16) u16 ls[64 * 136];  // [q][d]
  int t = threadIdx.x;
  int hh = blockIdx.x;
  if (hh >= 24) {  // V-copy: 131072 uint4 chunks over 64 blocks x 8 iters
    int blk = (hh - 24) * 16 + blockIdx.y;  // 0..63
#pragma unroll
    for (int it = 0; it < 8; ++it) {
      int i = blk * 2048 + it * 256 + t;
      int row = i >> 7, ch = i & 127;
      *(uint4*)(vT + (size_t)row * SEFF + CPOS + ch * 8) =
          *(const uint4*)(qkv + (size_t)(3072 + row) * NQ + ch * 8);
    }
    return;
  }
  int q0 = blockIdx.y * 64;
  bool isq = hh < 16;
  int rowbase = isq ? hh * DHEAD : HID + (hh - 16) * DHEAD;
#pragma unroll
  for (int it = 0; it < 4; ++it) {
    int c = it * 256 + t;
    int d = c >> 3, qc = (c & 7) * 8;
    U4 v;
    v.v = *(const uint4*)(qkv + (size_t)(rowbase + d) * NQ + q0 + qc);
#pragma unroll
    for (int e = 0; e < 8; ++e) ls[(qc + e) * 136 + d] = v.u[e];
  }
  __syncthreads();
  int ql = t & 63, hf = t >> 6;
  int q = q0 + ql;
  float scale = isq ? 0.08838834764831845f : 1.0f;
  u16* dst = isq ? (qb + ((size_t)hh * NQ + q) * DHEAD)
                 : (kb + ((size_t)(hh - 16) * SEFF + CPOS + q) * DHEAD);
#pragma unroll
  for (int g = 0; g < 4; ++g) {
    int d0 = hf * 32 + g * 8;
    U4 x, y;
    x.v = *(uint4*)(ls + ql * 136 + d0);
    y.v = *(uint4*)(ls + ql * 136 + (d0 ^ 64));
    float4 ca = *(const float4*)(cosb + (size_t)q * DHEAD + d0);
    float4 cb = *(const float4*)(cosb + (size_t)q * DHEAD + d0 + 4);
    float4 sa = *(const float4*)(sinb + (size_t)q * DHEAD + d0);
    float4 sb = *(const float4*)(sinb + (size_t)q * DHEAD + d0 + 4);
    float cs[8] = {ca.x, ca.y, ca.z, ca.w, cb.x, cb.y, cb.z, cb.w};
    float sn[8] = {sa.x, sa.y, sa.z, sa.w, sb.x, sb.y, sb.z, sb.w};
    float sgn = (d0 < 64) ? -1.0f : 1.0f;
    u32 ob[4];
#pragma unroll
    for (int e = 0; e < 4; ++e) {
      float r0 = (b2f(x.u[2 * e]) * cs[2 * e] + sgn * b2f(y.u[2 * e]) * sn[2 * e]) * scale;
      float r1 = (b2f(x.u[2 * e + 1]) * cs[2 * e + 1] + sgn * b2f(y.u[2 * e + 1]) * sn[2 * e + 1]) * scale;
      ob[e] = pk2(f2b(r0), f2b(r1));
    }
    *(uint4*)(dst + d0) = make_uint4(ob[0], ob[1], ob[2], ob[3]);
  }
}

// GEMM1: qkv = Wb @ hT^T + bias. 64x64 tiles, BK=64, grid (64,16)=1024
// -> 4 blocks/CU, 32 barriers. Measured optimum (R8 = 328.3us).
__global__ void __launch_bounds__(256) k_gemm_qkv(
    const u16* __restrict__ Wb, const u16* __restrict__ hT, u16* __restrict__ qkv,
    const float* __restrict__ bq, const float* __restrict__ bk, const float* __restrict__ bv) {
  __shared__ __align__(16) u16 lsA[2][2][64 * 32];  // [dbuf][khalf][row*32+col]
  __shared__ __align__(16) u16 lsB[2][2][64 * 32];
  int t = threadIdx.x;
  int m0 = blockIdx.x * 64, n0 = blockIdx.y * 64;
  const u16* Abase = Wb + (size_t)m0 * HID;
  const u16* Bbase = hT + (size_t)n0 * HID;
  int lane = t & 63, wid = t >> 6;
  int quad = lane >> 4, l15 = lane & 15;
  int wr = wid >> 1, wc = wid & 1;
  int sr = t >> 2, scol = (t & 3) * 8;
  f32x4 acc[2][2];
#pragma unroll
  for (int i = 0; i < 2; ++i)
#pragma unroll
    for (int j = 0; j < 2; ++j) acc[i][j] = (f32x4){0.f, 0.f, 0.f, 0.f};
  gld16(Abase + (size_t)sr * HID + scol, lsA[0][0] + t * 8);
  gld16(Abase + (size_t)sr * HID + 32 + scol, lsA[0][1] + t * 8);
  gld16(Bbase + (size_t)sr * HID + scol, lsB[0][0] + t * 8);
  gld16(Bbase + (size_t)sr * HID + 32 + scol, lsB[0][1] + t * 8);
  __syncthreads();
  int cur = 0;
  for (int kt = 0; kt < HID; kt += 64) {
    int kn = kt + 64;
    if (kn < HID) {
      gld16(Abase + (size_t)sr * HID + kn + scol, lsA[cur ^ 1][0] + t * 8);
      gld16(Abase + (size_t)sr * HID + kn + 32 + scol, lsA[cur ^ 1][1] + t * 8);
      gld16(Bbase + (size_t)sr * HID + kn + scol, lsB[cur ^ 1][0] + t * 8);
      gld16(Bbase + (size_t)sr * HID + kn + 32 + scol, lsB[cur ^ 1][1] + t * 8);
    }
#pragma unroll
    for (int kk = 0; kk < 2; ++kk) {
      bf16x8 af[2], bfr[2];
#pragma unroll
      for (int i = 0; i < 2; ++i)
        af[i] = *(const bf16x8*)(lsA[cur][kk] + (wr * 32 + i * 16 + l15) * 32 + quad * 8);
#pragma unroll
      for (int j = 0; j < 2; ++j)
        bfr[j] = *(const bf16x8*)(lsB[cur][kk] + (wc * 32 + j * 16 + l15) * 32 + quad * 8);
#pragma unroll
      for (int i = 0; i < 2; ++i)
#pragma unroll
        for (int j = 0; j < 2; ++j)
          acc[i][j] = __builtin_amdgcn_mfma_f32_16x16x32_bf16(af[i], bfr[j], acc[i][j], 0, 0, 0);
    }
    __syncthreads();
    cur ^= 1;
  }
#pragma unroll
  for (int i = 0; i < 2; ++i) {
#pragma unroll
    for (int r = 0; r < 4; ++r) {
      int m = m0 + wr * 32 + i * 16 + quad * 4 + r;
      float bias = (m < 2048) ? bq[m] : ((m < 3072) ? bk[m - 2048] : bv[m - 3072]);
#pragma unroll
      for (int j = 0; j < 2; ++j) {
        int n = n0 + wc * 32 + j * 16 + l15;
        qkv[(size_t)m * NQ + n] = f2b(acc[i][j][r] + bias);
      }
    }
  }
}

// Flash attention: grid (h, qt8, z=4), 512 threads (8 waves x 16 q-rows = 128 q/block).
// R8 structure (84.6us) + T5 s_setprio around the two MFMA clusters (QK, PV).
// Mechanism: each CU hosts 2 INDEPENDENT blocks (not barrier-synced with each
// other), so waves at MFMA phase can be favored over the other block's waves
// at softmax/staging phase (m191: +4-7% on phase-diverse attn; m190: null on
// lockstep GEMM — our cross-block diversity is the m191 case). Zero VGPR cost
// (cliff-safe), 4 SALU/iter. Everything else byte-identical to R8/R11.
__global__ void __launch_bounds__(512) k_flash(const u16* __restrict__ qb,
                                               const u16* __restrict__ kb,
                                               const u16* __restrict__ vT,
                                               u16* __restrict__ po,
                                               float* __restrict__ pm,
                                               float* __restrict__ pl) {
  __shared__ __align__(16) u16 lsK[64 * 136];   // (s, d) row stride 272B
  __shared__ __align__(16) u16 lsV[128 * 72];   // (d, s) row stride 144B
  __shared__ __align__(16) u16 lsP[8 * 16 * 72];
  int t = threadIdx.x;
  int h = blockIdx.x, qt = blockIdx.y, z = blockIdx.z;
  int kv = h >> 1;
  int q0 = qt * 128;
  int lane = t & 63, wid = t >> 6;
  int quad = lane >> 4, l15 = lane & 15;
  int qw = q0 + wid * 16;

  // constant ones fragment (bf16 1.0) for the denominator MFMA
  union { u16 u[8]; bf16x8 v; } onesu;
#pragma unroll
  for (int e = 0; e < 8; ++e) onesu.u[e] = 0x3f80;
  bf16x8 onesf = onesu.v;

  bf16x8 qf[4];
  const u16* qrow = qb + ((size_t)h * NQ + qw + l15) * DHEAD;
#pragma unroll
  for (int kc = 0; kc < 4; ++kc) qf[kc] = *(const bf16x8*)(qrow + kc * 32 + quad * 8);
  f32x4 oacc[8];
#pragma unroll
  for (int f = 0; f < 8; ++f) oacc[f] = (f32x4){0.f, 0.f, 0.f, 0.f};
  f32x4 lacc = (f32x4){0.f, 0.f, 0.f, 0.f};
  float m_run[4];
#pragma unroll
  for (int r = 0; r < 4; ++r) m_run[r] = -1e30f;
  u16* lsPw = lsP + wid * (16 * 72);
  int Svis = CPOS + q0 + 128;
  const u16* kbase = kb + (size_t)kv * SEFF * DHEAD;
  const u16* vbase = vT + (size_t)kv * DHEAD * SEFF;

  // T14 register staging: each thread owns 2 K chunks + 2 V chunks (static coords).
  int rK = t >> 4, cK = (t & 15) * 8;  // K: 64 rows x 128 u16
  int rV = t >> 3, cV = (t & 7) * 8;   // V: 128 rows x 64 u16
  uint4 pk0, pk1, pv0, pv1;
  {
    int s0 = z * 64;
    pk0 = *(const uint4*)(kbase + (size_t)(s0 + rK) * DHEAD + cK);
    pk1 = *(const uint4*)(kbase + (size_t)(s0 + 32 + rK) * DHEAD + cK);
    pv0 = *(const uint4*)(vbase + (size_t)rV * SEFF + s0 + cV);
    pv1 = *(const uint4*)(vbase + (size_t)(64 + rV) * SEFF + s0 + cV);
  }
  for (int s0 = z * 64; s0 < Svis; s0 += 256) {
    __syncthreads();  // all waves done reading previous tile's LDS
    *(uint4*)(lsK + rK * 136 + cK) = pk0;
    *(uint4*)(lsK + (32 + rK) * 136 + cK) = pk1;
    *(uint4*)(lsV + rV * 72 + cV) = pv0;
    *(uint4*)(lsV + (64 + rV) * 72 + cV) = pv1;
    __syncthreads();  // tile visible
    int sn = s0 + 256;
    if (sn < Svis) {  // issue next tile's loads; complete under compute
      pk0 = *(const uint4*)(kbase + (size_t)(sn + rK) * DHEAD + cK);
      pk1 = *(const uint4*)(kbase + (size_t)(sn + 32 + rK) * DHEAD + cK);
      pv0 = *(const uint4*)(vbase + (size_t)rV * SEFF + sn + cV);
      pv1 = *(const uint4*)(vbase + (size_t)(64 + rV) * SEFF + sn + cV);
    }
    f32x4 sc[4];
    __builtin_amdgcn_s_setprio(1);  // T5: favor this wave through the QK MFMA cluster
#pragma unroll
    for (int js = 0; js < 4; ++js) {
      sc[js] = (f32x4){0.f, 0.f, 0.f, 0.f};
#pragma unroll
      for (int kc = 0; kc < 4; ++kc) {
        bf16x8 kf = *(const bf16x8*)(lsK + (js * 16 + l15) * 136 + kc * 32 + quad * 8);
        sc[js] = __builtin_amdgcn_mfma_f32_16x16x32_bf16(qf[kc], kf, sc[js], 0, 0, 0);
      }
    }
    __builtin_amdgcn_s_setprio(0);
    if (s0 + 63 > CPOS + qw) {  // boundary tile for this wave: causal mask
#pragma unroll
      for (int r = 0; r < 4; ++r) {
        int lim = CPOS + qw + quad * 4 + r - s0;
#pragma unroll
        for (int js = 0; js < 4; ++js) {
          bool valid = (js * 16 + l15) <= lim;
          sc[js][r] = valid ? sc[js][r] : -1e30f;
        }
      }
    }
    float alpha[4];
#pragma unroll
    for (int r = 0; r < 4; ++r) {
      float mx = fmaxf(fmaxf(sc[0][r], sc[1][r]), fmaxf(sc[2][r], sc[3][r]));
      mx = fmaxf(mx, __shfl_xor(mx, 1, 64));
      mx = fmaxf(mx, __shfl_xor(mx, 2, 64));
      mx = fmaxf(mx, __shfl_xor(mx, 4, 64));
      mx = fmaxf(mx, __shfl_xor(mx, 8, 64));
      float mnew = fmaxf(m_run[r], mx);
      alpha[r] = __expf(m_run[r] - mnew);
      m_run[r] = mnew;
#pragma unroll
      for (int js = 0; js < 4; ++js) {
        float p = __expf(sc[js][r] - mnew);
        lsPw[(quad * 4 + r) * 72 + js * 16 + l15] = f2b_t(p);
      }
    }
#pragma unroll
    for (int f = 0; f < 8; ++f)
#pragma unroll
      for (int r = 0; r < 4; ++r) oacc[f][r] *= alpha[r];
#pragma unroll
    for (int r = 0; r < 4; ++r) lacc[r] *= alpha[r];
    bf16x8 pf[2];
#pragma unroll
    for (int ks = 0; ks < 2; ++ks)
      pf[ks] = *(const bf16x8*)(lsPw + l15 * 72 + ks * 32 + quad * 8);
    __builtin_amdgcn_s_setprio(1);  // T5: PV + denominator MFMA cluster
#pragma unroll
    for (int f = 0; f < 8; ++f) {
#pragma unroll
      for (int ks = 0; ks < 2; ++ks) {
        bf16x8 vf = *(const bf16x8*)(lsV + (f * 16 + l15) * 72 + ks * 32 + quad * 8);
        oacc[f] = __builtin_amdgcn_mfma_f32_16x16x32_bf16(pf[ks], vf, oacc[f], 0, 0, 0);
      }
    }
#pragma unroll
    for (int ks = 0; ks < 2; ++ks)
      lacc = __builtin_amdgcn_mfma_f32_16x16x32_bf16(pf[ks], onesf, lacc, 0, 0, 0);
    __builtin_amdgcn_s_setprio(0);
  }
  int p = (h * 8 + qt) * 4 + z;
#pragma unroll
  for (int r = 0; r < 4; ++r) {
    int qloc = wid * 16 + quad * 4 + r;  // 0..127
    if (l15 == 0) {
      pm[(size_t)p * 128 + qloc] = m_run[r];
      pl[(size_t)p * 128 + qloc] = lacc[r];  // running sum_s P
    }
#pragma unroll
    for (int f = 0; f < 8; ++f)
      po[(size_t)p * 16384 + qloc * 128 + f * 16 + l15] = f2b(oacc[f][r]);
  }
}

// Combine 4 S-split partials -> outT (NQ, H*D) bf16; grid (16,32):
//   by < 16 : combine (h = bx, qt = by)
//   by >= 16: Wo f32 -> bf16 streaming convert (absorbed launch)
__global__ void __launch_bounds__(256) k_combine(const u16* __restrict__ po,
                                                 const float* __restrict__ pm,
                                                 const float* __restrict__ pl,
                                                 u16* __restrict__ outT,
                                                 const float* __restrict__ Wo,
                                                 u16* __restrict__ Wob) {
  int t = threadIdx.x;
  int h = blockIdx.x;
  if (blockIdx.y >= 16) {  // Wo convert: 1,048,576 float4 over 256 blocks
    int blk = h * 16 + (blockIdx.y - 16);  // 0..255
#pragma unroll
    for (int k = 0; k < 16; ++k) {
      int i = blk * 256 + t + k * 65536;
      float4 v = ((const float4*)Wo)[i];
      *(uint2*)(Wob + (size_t)i * 4) = f4b4(v);
    }
    return;
  }
  int qt = blockIdx.y;
  int q = qt * 64 + (t >> 2);  // 0..1023
  int dq = (t & 3) * 32;
  int pb = (h * 8 + (q >> 7)) * 4;
  int ql = q & 127;
  float m0 = pm[(size_t)(pb + 0) * 128 + ql];
  float m1 = pm[(size_t)(pb + 1) * 128 + ql];
  float m2 = pm[(size_t)(pb + 2) * 128 + ql];
  float m3 = pm[(size_t)(pb + 3) * 128 + ql];
  float M = fmaxf(fmaxf(m0, m1), fmaxf(m2, m3));
  float w[4] = {__expf(m0 - M), __expf(m1 - M), __expf(m2 - M), __expf(m3 - M)};
  float L = 0.f;
#pragma unroll
  for (int zz = 0; zz < 4; ++zz) L += w[zz] * pl[(size_t)(pb + zz) * 128 + ql];
  float acc[32];
#pragma unroll
  for (int e = 0; e < 32; ++e) acc[e] = 0.f;
#pragma unroll
  for (int zz = 0; zz < 4; ++zz) {
    const u16* src = po + (size_t)(pb + zz) * 16384 + ql * 128 + dq;
#pragma unroll
    for (int j = 0; j < 4; ++j) {
      U4 v;
      v.v = *(const uint4*)(src + j * 8);
#pragma unroll
      for (int e = 0; e < 8; ++e) acc[j * 8 + e] += w[zz] * b2f(v.u[e]);
    }
  }
  float inv = 1.0f / L;
  u16* dst = outT + (size_t)q * HID + h * DHEAD + dq;
#pragma unroll
  for (int j = 0; j < 4; ++j) {
    u32 ob[4];
#pragma unroll
    for (int e = 0; e < 4; ++e)
      ob[e] = pk2(f2b(acc[j * 8 + 2 * e] * inv), f2b(acc[j * 8 + 2 * e + 1] * inv));
    *(uint4*)(dst + j * 8) = make_uint4(ob[0], ob[1], ob[2], ob[3]);
  }
}

// GEMM2: out f32 = Wob bf16 @ attn; B^T = outT. 64x64 tiles, BK=64,
// dbuf gld16, grid (32,16)=512 (R8 measured optimum).
__global__ void __launch_bounds__(256) k_gemm_bt(const u16* __restrict__ A,
                                                 const u16* __restrict__ BT,
                                                 float* __restrict__ C) {
  __shared__ __align__(16) u16 lsA[2][2][64 * 32];
  __shared__ __align__(16) u16 lsB[2][2][64 * 32];
  int t = threadIdx.x;
  int m0 = blockIdx.x * 64, n0 = blockIdx.y * 64;
  const u16* Abase = A + (size_t)m0 * HID;
  const u16* Bbase = BT + (size_t)n0 * HID;
  int lane = t & 63, wid = t >> 6;
  int quad = lane >> 4, l15 = lane & 15;
  int wr = wid >> 1, wc = wid & 1;
  int sr = t >> 2, scol = (t & 3) * 8;
  f32x4 acc[2][2];
#pragma unroll
  for (int i = 0; i < 2; ++i)
#pragma unroll
    for (int j = 0; j < 2; ++j) acc[i][j] = (f32x4){0.f, 0.f, 0.f, 0.f};
  gld16(Abase + (size_t)sr * HID + scol, lsA[0][0] + t * 8);
  gld16(Abase + (size_t)sr * HID + 32 + scol, lsA[0][1] + t * 8);
  gld16(Bbase + (size_t)sr * HID + scol, lsB[0][0] + t * 8);
  gld16(Bbase + (size_t)sr * HID + 32 + scol, lsB[0][1] + t * 8);
  __syncthreads();
  int cur = 0;
  for (int kt = 0; kt < HID; kt += 64) {
    int kn = kt + 64;
    if (kn < HID) {
      gld16(Abase + (size_t)sr * HID + kn + scol, lsA[cur ^ 1][0] + t * 8);
      gld16(Abase + (size_t)sr * HID + kn + 32 + scol, lsA[cur ^ 1][1] + t * 8);
      gld16(Bbase + (size_t)sr * HID + kn + scol, lsB[cur ^ 1][0] + t * 8);
      gld16(Bbase + (size_t)sr * HID + kn + 32 + scol, lsB[cur ^ 1][1] + t * 8);
    }
#pragma unroll
    for (int kk = 0; kk < 2; ++kk) {
      bf16x8 af[2], bfr[2];
#pragma unroll
      for (int i = 0; i < 2; ++i)
        af[i] = *(const bf16x8*)(lsA[cur][kk] + (wr * 32 + i * 16 + l15) * 32 + quad * 8);
#pragma unroll
      for (int j = 0; j < 2; ++j)
        bfr[j] = *(const bf16x8*)(lsB[cur][kk] + (wc * 32 + j * 16 + l15) * 32 + quad * 8);
#pragma unroll
      for (int i = 0; i < 2; ++i)
#pragma unroll
        for (int j = 0; j < 2; ++j)
          acc[i][j] = __builtin_amdgcn_mfma_f32_16x16x32_bf16(af[i], bfr[j], acc[i][j], 0, 0, 0);
    }
    __syncthreads();
    cur ^= 1;
  }
#pragma unroll
  for (int i = 0; i < 2; ++i)
#pragma unroll
    for (int r = 0; r < 4; ++r) {
      int m = m0 + wr * 32 + i * 16 + quad * 4 + r;
#pragma unroll
      for (int j = 0; j < 2; ++j) {
        int n = n0 + wc * 32 + j * 16 + l15;
        C[(size_t)m * NQ + n] = acc[i][j][r];
      }
    }
}

extern "C" void kernel_launch(void* const* d_in, const int* in_sizes, int n_in,
                              void* d_out, int out_size, void* d_ws, size_t ws_size,
                              hipStream_t stream) {
  (void)in_sizes; (void)n_in; (void)out_size; (void)ws_size;
  const float* hidden = (const float*)d_in[0];
  const float* cosb = (const float*)d_in[1];
  const float* sinb = (const float*)d_in[2];
  const float* kcache = (const float*)d_in[6];
  const float* vcache = (const float*)d_in[7];
  const float* Wq = (const float*)d_in[8];
  const float* bq = (const float*)d_in[9];
  const float* Wk = (const float*)d_in[10];
  const float* bk = (const float*)d_in[11];
  const float* Wv = (const float*)d_in[12];
  const float* bv = (const float*)d_in[13];
  const float* Wo = (const float*)d_in[14];

  char* ws = (char*)d_ws;
  u16* qkv = (u16*)(ws);                    // [0 .. 8,388,608)
  u16* outT = (u16*)(ws + 8388608);         // [8,388,608 .. 12,582,912); hT overlays
  u16* hT = outT;
  u16* vT = (u16*)(ws + 12582912);          // [12,582,912 .. 23,068,672)
  u16* Wob = vT;                            // overlay: vT dead after flash
  u16* kb = (u16*)(ws + 23068672);          // [23,068,672 .. 33,554,432)
  u16* qb = (u16*)(ws + 33554432);          // [33,554,432 .. 37,748,736)
  u16* po = (u16*)(ws + 37748736);          // [37,748,736 .. 54,525,952)
  u16* Wb = po;                             // overlay: Wb dead after gemm1, po written by flash
  float* pm = (float*)(ws + 54525952);      // 256 KB
  float* pl = (float*)(ws + 54788096);      // 256 KB  (total ws 55,050,240)
  float* outb = (float*)d_out;

  k_prep_all<<<13824, 256, 0, stream>>>(hidden, hT, vcache, vT, Wq, Wk, Wv, kcache, Wb, kb);
  k_gemm_qkv<<<dim3(64, 16), 256, 0, stream>>>(Wb, hT, qkv, bq, bk, bv);
  // Wb dead from here; flash reuses its region as po
  k_rope_t<<<dim3(28, 16), 256, 0, stream>>>(qkv, cosb, sinb, qb, kb, vT);
  k_flash<<<dim3(16, 8, 4), 512, 0, stream>>>(qb, kb, vT, po, pm, pl);
  k_combine<<<dim3(16, 32), 256, 0, stream>>>(po, pm, pl, outT, Wo, Wob);
  k_gemm_bt<<<dim3(32, 16), 256, 0, stream>>>(Wob, outT, outb);
}